// Round 3
// baseline (123.166 us; speedup 1.0000x reference)
//
#include <hip/hip_runtime.h>

#define NB 256
#define NJ 24
#define NV 6890

// ---------------------------------------------------------------------------
// Kernel 1: per-batch kinematic chain. One thread per batch element.
// Writes posed_joints (B,J,3) and rel_transforms (B,J,4,4) into d_out slices.
// ---------------------------------------------------------------------------
__global__ __launch_bounds__(32) void chain_kernel(
    const float* __restrict__ rot,      // (B,J,3,3)
    const float* __restrict__ joints,   // (B,J,3)
    float* __restrict__ posed_joints,   // (B,J,3)
    float* __restrict__ rel_tf)         // (B,J,4,4)
{
    constexpr int parents[NJ] = {0,0,0,0,1,2,3,4,5,6,7,8,9,9,9,12,13,14,16,17,18,19,20,21};
    // Per-thread chain history in LDS, lane-major: [(j*12+e)*32 + t] -> stride-1
    // across lanes -> conflict-free (2 lanes/bank for wave64 is free).
    __shared__ float Alds[NJ * 12 * 32];
    const int t = threadIdx.x;
    const int b = blockIdx.x * 32 + t;
    if (b >= NB) return;

    const float* jb = joints + (size_t)b * NJ * 3;
    const float* rb = rot + (size_t)b * NJ * 9;
    float* pj = posed_joints + (size_t)b * NJ * 3;
    float* rt = rel_tf + (size_t)b * NJ * 16;

    float jx[NJ], jy[NJ], jz[NJ];
#pragma unroll
    for (int j = 0; j < NJ; ++j) {
        jx[j] = jb[j * 3 + 0];
        jy[j] = jb[j * 3 + 1];
        jz[j] = jb[j * 3 + 2];
    }

#pragma unroll
    for (int j = 0; j < NJ; ++j) {
        float R[9];
#pragma unroll
        for (int e = 0; e < 9; ++e) R[e] = rb[j * 9 + e];

        float tx, ty, tz;
        if (j == 0) {
            tx = jx[0]; ty = jy[0]; tz = jz[0];
        } else {
            const int p = parents[j];
            tx = jx[j] - jx[p];
            ty = jy[j] - jy[p];
            tz = jz[j] - jz[p];
        }

        float A[12];
        if (j == 0) {
            A[0] = R[0]; A[1] = R[1]; A[2]  = R[2]; A[3]  = tx;
            A[4] = R[3]; A[5] = R[4]; A[6]  = R[5]; A[7]  = ty;
            A[8] = R[6]; A[9] = R[7]; A[10] = R[8]; A[11] = tz;
        } else {
            const int p = parents[j];
            float P[12];
#pragma unroll
            for (int e = 0; e < 12; ++e) P[e] = Alds[(p * 12 + e) * 32 + t];
#pragma unroll
            for (int r = 0; r < 3; ++r) {
                const float pr0 = P[r * 4 + 0], pr1 = P[r * 4 + 1];
                const float pr2 = P[r * 4 + 2], pr3 = P[r * 4 + 3];
                A[r * 4 + 0] = pr0 * R[0] + pr1 * R[3] + pr2 * R[6];
                A[r * 4 + 1] = pr0 * R[1] + pr1 * R[4] + pr2 * R[7];
                A[r * 4 + 2] = pr0 * R[2] + pr1 * R[5] + pr2 * R[8];
                A[r * 4 + 3] = pr0 * tx + pr1 * ty + pr2 * tz + pr3;
            }
        }
#pragma unroll
        for (int e = 0; e < 12; ++e) Alds[(j * 12 + e) * 32 + t] = A[e];

        // posed_joints = A[:, :, :3, 3]
        pj[j * 3 + 0] = A[3];
        pj[j * 3 + 1] = A[7];
        pj[j * 3 + 2] = A[11];

        // rel_transforms: col 3 -= A[:, :3] @ joints_j ; bottom row = 0,0,0,1
        const float jjx = jx[j], jjy = jy[j], jjz = jz[j];
#pragma unroll
        for (int r = 0; r < 3; ++r) {
            rt[j * 16 + r * 4 + 0] = A[r * 4 + 0];
            rt[j * 16 + r * 4 + 1] = A[r * 4 + 1];
            rt[j * 16 + r * 4 + 2] = A[r * 4 + 2];
            rt[j * 16 + r * 4 + 3] =
                A[r * 4 + 3] - (A[r * 4 + 0] * jjx + A[r * 4 + 1] * jjy + A[r * 4 + 2] * jjz);
        }
        rt[j * 16 + 12] = 0.0f;
        rt[j * 16 + 13] = 0.0f;
        rt[j * 16 + 14] = 0.0f;
        rt[j * 16 + 15] = 1.0f;
    }
}

// ---------------------------------------------------------------------------
// Kernel 2: vertex blend. One block per (batch, 512-vertex chunk), 2 verts/thread.
// ---------------------------------------------------------------------------
#define VPB 512

__global__ __launch_bounds__(256) void lbs_kernel(
    const float* __restrict__ verts,    // (B,V,3)
    const float* __restrict__ weights,  // (V,J)
    const float* __restrict__ rel_tf,   // (B,J,4,4)
    float* __restrict__ out_verts)      // (B,V,3)
{
    __shared__ float Ms[NJ * 12];   // rows 0..2 of each joint's 4x4
    const int tid = threadIdx.x;
    const int b = blockIdx.y;

    // NJ*12 = 288 > blockDim(256): MUST stride (round-2 bug: joints 21..23
    // were never staged -> uninitialized LDS blended into the output).
    for (int i = tid; i < NJ * 12; i += 256) {
        const int j = i / 12;
        const int e = i % 12;             // e = r*4+c, r<3
        Ms[i] = rel_tf[((size_t)b * NJ + j) * 16 + e];
    }
    __syncthreads();

    const int v0 = blockIdx.x * VPB + tid * 2;
    if (v0 >= NV) return;

    // 48 consecutive weights (vertex v0 then v0+1); v0*96 bytes -> 16B aligned
    const float4* w4 = reinterpret_cast<const float4*>(weights + (size_t)v0 * NJ);
    float wreg[2 * NJ];
#pragma unroll
    for (int i = 0; i < 12; ++i) {
        const float4 q = w4[i];
        wreg[i * 4 + 0] = q.x;
        wreg[i * 4 + 1] = q.y;
        wreg[i * 4 + 2] = q.z;
        wreg[i * 4 + 3] = q.w;
    }

    // 6 floats of vertex data; (b*NV+v0) even -> 8B aligned
    const float2* vp = reinterpret_cast<const float2*>(verts + ((size_t)b * NV + v0) * 3);
    const float2 p0 = vp[0], p1 = vp[1], p2 = vp[2];
    const float x0 = p0.x, y0 = p0.y, z0 = p1.x;
    const float x1 = p1.y, y1 = p2.x, z1 = p2.y;

    float acc0[12], acc1[12];
#pragma unroll
    for (int e = 0; e < 12; ++e) { acc0[e] = 0.0f; acc1[e] = 0.0f; }

#pragma unroll
    for (int j = 0; j < NJ; ++j) {
        const float w0 = wreg[j];
        const float w1 = wreg[NJ + j];
#pragma unroll
        for (int e = 0; e < 12; ++e) {
            const float m = Ms[j * 12 + e];   // LDS broadcast (same addr all lanes)
            acc0[e] += w0 * m;
            acc1[e] += w1 * m;
        }
    }

    float o[6];
    o[0] = acc0[0] * x0 + acc0[1] * y0 + acc0[2]  * z0 + acc0[3];
    o[1] = acc0[4] * x0 + acc0[5] * y0 + acc0[6]  * z0 + acc0[7];
    o[2] = acc0[8] * x0 + acc0[9] * y0 + acc0[10] * z0 + acc0[11];
    o[3] = acc1[0] * x1 + acc1[1] * y1 + acc1[2]  * z1 + acc1[3];
    o[4] = acc1[4] * x1 + acc1[5] * y1 + acc1[6]  * z1 + acc1[7];
    o[5] = acc1[8] * x1 + acc1[9] * y1 + acc1[10] * z1 + acc1[11];

    float2* op = reinterpret_cast<float2*>(out_verts + ((size_t)b * NV + v0) * 3);
    op[0] = make_float2(o[0], o[1]);
    op[1] = make_float2(o[2], o[3]);
    op[2] = make_float2(o[4], o[5]);
}

extern "C" void kernel_launch(void* const* d_in, const int* in_sizes, int n_in,
                              void* d_out, int out_size, void* d_ws, size_t ws_size,
                              hipStream_t stream) {
    const float* rot     = (const float*)d_in[0];   // (B,J,3,3)
    const float* joints  = (const float*)d_in[1];   // (B,J,3)
    const float* verts   = (const float*)d_in[2];   // (B,V,3)
    const float* weights = (const float*)d_in[3];   // (V,J)

    float* out = (float*)d_out;
    float* posed_verts  = out;                                   // B*V*3
    float* posed_joints = out + (size_t)NB * NV * 3;             // B*J*3
    float* rel_tf       = posed_joints + (size_t)NB * NJ * 3;    // B*J*16

    chain_kernel<<<dim3(NB / 32), dim3(32), 0, stream>>>(rot, joints, posed_joints, rel_tf);

    const int nblk = (NV + VPB - 1) / VPB;   // 14
    lbs_kernel<<<dim3(nblk, NB), dim3(256), 0, stream>>>(verts, weights, rel_tf, posed_verts);
}